// Round 1
// baseline (506.985 us; speedup 1.0000x reference)
//
#include <hip/hip_runtime.h>

constexpr int N_NODES  = 4000000;
constexpr int N_GRAPHS = 4096;
constexpr int D_FEAT   = 8;
constexpr int N_CLS    = 10;
constexpr int NPT      = 8;   // nodes per thread (4M % 8 == 0)

__device__ __forceinline__ void flush_seg(float* __restrict__ sums,
                                          float* __restrict__ cnts,
                                          int seg, const float4& a0,
                                          const float4& a1, float cnt) {
    float* s = sums + (size_t)seg * D_FEAT;
    atomicAdd(s + 0, a0.x);
    atomicAdd(s + 1, a0.y);
    atomicAdd(s + 2, a0.z);
    atomicAdd(s + 3, a0.w);
    atomicAdd(s + 4, a1.x);
    atomicAdd(s + 5, a1.y);
    atomicAdd(s + 6, a1.z);
    atomicAdd(s + 7, a1.w);
    atomicAdd(cnts + seg, cnt);
}

__global__ __launch_bounds__(256) void seg_accum(
    const float4* __restrict__ x4,     // [N_NODES*2] (two float4 per node)
    const int*    __restrict__ ids,    // [N_NODES] sorted
    float*        __restrict__ sums,   // [N_GRAPHS*D_FEAT]
    float*        __restrict__ cnts)   // [N_GRAPHS]
{
    int tid   = blockIdx.x * blockDim.x + threadIdx.x;
    int start = tid * NPT;
    if (start >= N_NODES) return;
    int end = start + NPT;
    if (end > N_NODES) end = N_NODES;

    int first = ids[start];
    int last  = ids[end - 1];

    float4 a0 = make_float4(0.f, 0.f, 0.f, 0.f);
    float4 a1 = make_float4(0.f, 0.f, 0.f, 0.f);

    if (first == last) {
        // whole chunk in one segment — branchless accumulate
        #pragma unroll
        for (int i = 0; i < NPT; ++i) {
            int n = start + i;
            float4 v0 = x4[2 * (size_t)n];
            float4 v1 = x4[2 * (size_t)n + 1];
            a0.x += v0.x; a0.y += v0.y; a0.z += v0.z; a0.w += v0.w;
            a1.x += v1.x; a1.y += v1.y; a1.z += v1.z; a1.w += v1.w;
        }
        flush_seg(sums, cnts, first, a0, a1, (float)(end - start));
    } else {
        int   cur = first;
        float cnt = 0.f;
        for (int n = start; n < end; ++n) {
            int id = ids[n];
            if (id != cur) {
                flush_seg(sums, cnts, cur, a0, a1, cnt);
                a0 = make_float4(0.f, 0.f, 0.f, 0.f);
                a1 = make_float4(0.f, 0.f, 0.f, 0.f);
                cnt = 0.f;
                cur = id;
            }
            float4 v0 = x4[2 * (size_t)n];
            float4 v1 = x4[2 * (size_t)n + 1];
            a0.x += v0.x; a0.y += v0.y; a0.z += v0.z; a0.w += v0.w;
            a1.x += v1.x; a1.y += v1.y; a1.z += v1.z; a1.w += v1.w;
            cnt  += 1.f;
        }
        flush_seg(sums, cnts, cur, a0, a1, cnt);
    }
}

__global__ __launch_bounds__(256) void finalize(
    const float* __restrict__ sums,   // [N_GRAPHS*D_FEAT]
    const float* __restrict__ cnts,   // [N_GRAPHS]
    const float* __restrict__ W,      // [N_CLS, D_FEAT]
    const float* __restrict__ bias,   // [N_CLS]
    float*       __restrict__ out)    // [N_GRAPHS, N_CLS]
{
    int idx = blockIdx.x * blockDim.x + threadIdx.x;
    if (idx >= N_GRAPHS * N_CLS) return;
    int g = idx / N_CLS;
    int c = idx % N_CLS;

    float inv = 1.0f / cnts[g];
    const float* s = sums + (size_t)g * D_FEAT;
    const float* w = W + (size_t)c * D_FEAT;
    float acc = bias[c];
    #pragma unroll
    for (int j = 0; j < D_FEAT; ++j)
        acc += (s[j] * inv) * w[j];
    out[idx] = acc;
}

extern "C" void kernel_launch(void* const* d_in, const int* in_sizes, int n_in,
                              void* d_out, int out_size, void* d_ws, size_t ws_size,
                              hipStream_t stream) {
    const float* x   = (const float*)d_in[0];   // [4M, 8] f32
    const int*   ids = (const int*)d_in[1];     // [4M] sorted segment ids
    // d_in[2] input_ids, d_in[3] attention_mask: unused by the forward
    const float* W   = (const float*)d_in[4];   // [10, 8]
    const float* b   = (const float*)d_in[5];   // [10]
    float*       out = (float*)d_out;           // [4096, 10]

    float* sums = (float*)d_ws;                 // [4096*8]
    float* cnts = sums + (size_t)N_GRAPHS * D_FEAT;  // [4096]

    // zero the accumulators every call (ws is poisoned / not re-poisoned)
    hipMemsetAsync(d_ws, 0, (size_t)(N_GRAPHS * D_FEAT + N_GRAPHS) * sizeof(float),
                   stream);

    int nthreads = (N_NODES + NPT - 1) / NPT;        // 500,000
    int nblocks  = (nthreads + 255) / 256;           // 1954
    seg_accum<<<nblocks, 256, 0, stream>>>((const float4*)x, ids, sums, cnts);

    int fin_threads = N_GRAPHS * N_CLS;              // 40,960
    finalize<<<(fin_threads + 255) / 256, 256, 0, stream>>>(sums, cnts, W, b, out);
}

// Round 2
// 33.980 us; speedup vs baseline: 14.9201x; 14.9201x over previous
//
#include <hip/hip_runtime.h>

constexpr int N_NODES  = 4000000;
constexpr int N_GRAPHS = 4096;
constexpr int D_FEAT   = 8;
constexpr int N_CLS    = 10;

// Kernel A: bounds[g] = first index i with ids[i] >= g, for g in [0, N_GRAPHS].
// ids are sorted, so segment g occupies [bounds[g], bounds[g+1]).
__global__ __launch_bounds__(256) void find_bounds(
    const int* __restrict__ ids, int* __restrict__ bounds)
{
    int g = blockIdx.x * blockDim.x + threadIdx.x;
    if (g > N_GRAPHS) return;
    int lo = 0, hi = N_NODES;
    while (lo < hi) {
        int mid = (lo + hi) >> 1;
        if (ids[mid] < g) lo = mid + 1; else hi = mid;
    }
    bounds[g] = lo;
}

// Kernel B: one block per graph. Sum x[s:e] (8 feats), mean, then logits.
__global__ __launch_bounds__(256) void pool_linear(
    const float4* __restrict__ x4,     // [N_NODES*2] two float4 per node
    const int*    __restrict__ bounds, // [N_GRAPHS+1]
    const float*  __restrict__ W,      // [N_CLS, D_FEAT]
    const float*  __restrict__ bias,   // [N_CLS]
    float*        __restrict__ out)    // [N_GRAPHS, N_CLS]
{
    int g = blockIdx.x;
    int s = bounds[g];
    int e = bounds[g + 1];
    int len = e - s;

    float4 a0 = make_float4(0.f, 0.f, 0.f, 0.f);
    float4 a1 = make_float4(0.f, 0.f, 0.f, 0.f);

    // Coalesced: lane i loads the 32 B of node (s + i); the two back-to-back
    // dwordx4 loads fully cover a contiguous 2 KB span per wave iteration.
    for (int n = s + (int)threadIdx.x; n < e; n += 256) {
        float4 v0 = x4[2 * (size_t)n];
        float4 v1 = x4[2 * (size_t)n + 1];
        a0.x += v0.x; a0.y += v0.y; a0.z += v0.z; a0.w += v0.w;
        a1.x += v1.x; a1.y += v1.y; a1.z += v1.z; a1.w += v1.w;
    }

    // Wave (64-lane) butterfly reduction of the 8 partial sums.
    #pragma unroll
    for (int off = 32; off > 0; off >>= 1) {
        a0.x += __shfl_xor(a0.x, off);
        a0.y += __shfl_xor(a0.y, off);
        a0.z += __shfl_xor(a0.z, off);
        a0.w += __shfl_xor(a0.w, off);
        a1.x += __shfl_xor(a1.x, off);
        a1.y += __shfl_xor(a1.y, off);
        a1.z += __shfl_xor(a1.z, off);
        a1.w += __shfl_xor(a1.w, off);
    }

    __shared__ float red[4][D_FEAT];
    __shared__ float mean[D_FEAT];
    int wid  = threadIdx.x >> 6;
    int lane = threadIdx.x & 63;
    if (lane == 0) {
        red[wid][0] = a0.x; red[wid][1] = a0.y;
        red[wid][2] = a0.z; red[wid][3] = a0.w;
        red[wid][4] = a1.x; red[wid][5] = a1.y;
        red[wid][6] = a1.z; red[wid][7] = a1.w;
    }
    __syncthreads();
    if (threadIdx.x < D_FEAT) {
        float v = red[0][threadIdx.x] + red[1][threadIdx.x]
                + red[2][threadIdx.x] + red[3][threadIdx.x];
        mean[threadIdx.x] = v / (float)len;
    }
    __syncthreads();
    if (threadIdx.x < N_CLS) {
        const float* w = W + (size_t)threadIdx.x * D_FEAT;
        float acc = bias[threadIdx.x];
        #pragma unroll
        for (int j = 0; j < D_FEAT; ++j)
            acc += mean[j] * w[j];
        out[(size_t)g * N_CLS + threadIdx.x] = acc;
    }
}

extern "C" void kernel_launch(void* const* d_in, const int* in_sizes, int n_in,
                              void* d_out, int out_size, void* d_ws, size_t ws_size,
                              hipStream_t stream) {
    const float* x   = (const float*)d_in[0];   // [4M, 8] f32
    const int*   ids = (const int*)d_in[1];     // [4M] sorted segment ids
    // d_in[2] input_ids, d_in[3] attention_mask: unused by the forward
    const float* W   = (const float*)d_in[4];   // [10, 8]
    const float* b   = (const float*)d_in[5];   // [10]
    float*       out = (float*)d_out;           // [4096, 10]

    int* bounds = (int*)d_ws;                   // [N_GRAPHS+1]

    find_bounds<<<(N_GRAPHS + 1 + 255) / 256, 256, 0, stream>>>(ids, bounds);
    pool_linear<<<N_GRAPHS, 256, 0, stream>>>((const float4*)x, bounds, W, b, out);
}